// Round 1
// baseline (1689.644 us; speedup 1.0000x reference)
//
#include <hip/hip_runtime.h>
#include <math.h>

#define SEQ 4096
#define DM  768
#define NH  12
#define HD  64

// ---------------------------------------------------------------------------
// Fused QKV projection + RoPE.
// C = x(SEQ x DM) . W(N x DM)^T   for W in {wq, wk, wv}  (blockIdx.z selects)
// Output stored head-major [h][s][64]; RoPE applied for q and k.
// N-tile of 64 == exactly one head (HD == 64).
// ---------------------------------------------------------------------------
__global__ __launch_bounds__(256)
void qkv_rope_kernel(const float* __restrict__ x,
                     const float* __restrict__ wq,
                     const float* __restrict__ wk,
                     const float* __restrict__ wv,
                     const int*   __restrict__ tokpos,
                     float* __restrict__ Qo,
                     float* __restrict__ Ko,
                     float* __restrict__ Vo)
{
    __shared__ float As[64][65];   // As[k][m]  (k-major for float4 reads)
    __shared__ float Bs[64][65];   // Bs[k][n]
    const int tid = threadIdx.x;
    const int tx = tid & 15, ty = tid >> 4;
    const int mBase = blockIdx.x * 64;
    const int h     = blockIdx.y;
    const int which = blockIdx.z;
    const float* __restrict__ W = (which == 0) ? wq : (which == 1) ? wk : wv;
    float* __restrict__ C       = (which == 0) ? Qo : (which == 1) ? Ko : Vo;
    const int nBase = h * HD;

    float acc[4][4] = {};

    for (int k0 = 0; k0 < DM; k0 += 64) {
        #pragma unroll
        for (int l = 0; l < 16; ++l) {
            int idx = l * 256 + tid;
            int r = idx >> 6, c = idx & 63;          // coalesced: c follows tid
            As[c][r] = x[(size_t)(mBase + r) * DM + k0 + c];
            Bs[c][r] = W[(size_t)(nBase + r) * DM + k0 + c];
        }
        __syncthreads();
        #pragma unroll 16
        for (int kk = 0; kk < 64; ++kk) {
            const float4 av = *(const float4*)&As[kk][ty * 4];
            const float4 bv = *(const float4*)&Bs[kk][tx * 4];
            const float a[4] = {av.x, av.y, av.z, av.w};
            const float b[4] = {bv.x, bv.y, bv.z, bv.w};
            #pragma unroll
            for (int i = 0; i < 4; ++i)
                #pragma unroll
                for (int j = 0; j < 4; ++j)
                    acc[i][j] = fmaf(a[i], b[j], acc[i][j]);
        }
        __syncthreads();
    }

    if (which < 2) {
        // RoPE: pairs (2k, 2k+1); thread owns cols tx*4 .. tx*4+3 -> 2 pairs.
        #pragma unroll
        for (int i = 0; i < 4; ++i) {
            const float pos = (float)tokpos[mBase + ty * 4 + i];
            #pragma unroll
            for (int p = 0; p < 2; ++p) {
                const int kf = tx * 2 + p;                 // pair index 0..31
                // inv_freq = 10000^(-kf/32) = 2^(-kf * log2(1e4)/32)
                const float inv = exp2f((float)kf * (-13.287712379549449f / 32.0f));
                float sn, cs;
                sincosf(pos * inv, &sn, &cs);              // accurate range reduction
                const float e = acc[i][2 * p], o = acc[i][2 * p + 1];
                acc[i][2 * p]     = e * cs - o * sn;
                acc[i][2 * p + 1] = e * sn + o * cs;
            }
        }
    }

    #pragma unroll
    for (int i = 0; i < 4; ++i) {
        const int m = mBase + ty * 4 + i;
        float4 v = make_float4(acc[i][0], acc[i][1], acc[i][2], acc[i][3]);
        *(float4*)&C[((size_t)h * SEQ + m) * HD + tx * 4] = v;
    }
}

// ---------------------------------------------------------------------------
// Flash-style causal attention, fp32. One block per (head, 64-query tile).
// Online softmax; per-row state replicated across the 16 lanes of a row group.
// ---------------------------------------------------------------------------
__global__ __launch_bounds__(256)
void attn_kernel(const float* __restrict__ Q,
                 const float* __restrict__ K,
                 const float* __restrict__ V,
                 float* __restrict__ O)      // [SEQ][DM] row-major
{
    __shared__ float Qs[64][65];   // [d][m]
    __shared__ float Ks[64][65];   // [d][n]
    __shared__ float Vs[64][65];   // [c][d]
    __shared__ float Ps[64][65];   // [c][m]  (P transposed)
    const int tid = threadIdx.x;
    const int tx = tid & 15, ty = tid >> 4;
    const int h  = blockIdx.y;
    const int qb = (int)gridDim.x - 1 - (int)blockIdx.x;   // heavy blocks first
    const int q0 = qb * 64;
    const float* __restrict__ Qh = Q + (size_t)h * SEQ * HD;
    const float* __restrict__ Kh = K + (size_t)h * SEQ * HD;
    const float* __restrict__ Vh = V + (size_t)h * SEQ * HD;

    #pragma unroll
    for (int l = 0; l < 16; ++l) {
        int idx = l * 256 + tid;
        int r = idx >> 6, c = idx & 63;
        Qs[c][r] = Qh[(size_t)(q0 + r) * HD + c];
    }

    float o_acc[4][4] = {};
    float m_i[4], l_i[4];
    #pragma unroll
    for (int i = 0; i < 4; ++i) { m_i[i] = -1e30f; l_i[i] = 0.0f; }

    for (int kb = 0; kb <= qb; ++kb) {
        __syncthreads();   // prior-iter PV reads of Vs/Ps done before overwrite
        #pragma unroll
        for (int l = 0; l < 16; ++l) {
            int idx = l * 256 + tid;
            int r = idx >> 6, c = idx & 63;
            const float kval = Kh[(size_t)(kb * 64 + r) * HD + c];
            const float vval = Vh[(size_t)(kb * 64 + r) * HD + c];
            Ks[c][r] = kval;
            Vs[r][c] = vval;
        }
        __syncthreads();

        // S = Q . K^T  (64x64x64)
        float s[4][4] = {};
        #pragma unroll 16
        for (int kk = 0; kk < 64; ++kk) {
            const float4 qv = *(const float4*)&Qs[kk][ty * 4];
            const float4 kv = *(const float4*)&Ks[kk][tx * 4];
            const float qa[4] = {qv.x, qv.y, qv.z, qv.w};
            const float ka[4] = {kv.x, kv.y, kv.z, kv.w};
            #pragma unroll
            for (int i = 0; i < 4; ++i)
                #pragma unroll
                for (int j = 0; j < 4; ++j)
                    s[i][j] = fmaf(qa[i], ka[j], s[i][j]);
        }

        // scale + causal mask (only diagonal block needs masking)
        const bool diag = (kb == qb);
        #pragma unroll
        for (int i = 0; i < 4; ++i) {
            const int ri = ty * 4 + i;
            #pragma unroll
            for (int j = 0; j < 4; ++j) {
                float val = s[i][j] * 0.125f;
                if (diag && (tx * 4 + j > ri)) val = -1e30f;
                s[i][j] = val;
            }
        }

        // online softmax update, per row
        #pragma unroll
        for (int i = 0; i < 4; ++i) {
            float rmax = fmaxf(fmaxf(s[i][0], s[i][1]), fmaxf(s[i][2], s[i][3]));
            rmax = fmaxf(rmax, __shfl_xor(rmax, 1));
            rmax = fmaxf(rmax, __shfl_xor(rmax, 2));
            rmax = fmaxf(rmax, __shfl_xor(rmax, 4));
            rmax = fmaxf(rmax, __shfl_xor(rmax, 8));
            const float mnew  = fmaxf(m_i[i], rmax);
            const float alpha = __expf(m_i[i] - mnew);
            float rsum = 0.f;
            #pragma unroll
            for (int j = 0; j < 4; ++j) {
                s[i][j] = __expf(s[i][j] - mnew);
                rsum += s[i][j];
            }
            rsum += __shfl_xor(rsum, 1);
            rsum += __shfl_xor(rsum, 2);
            rsum += __shfl_xor(rsum, 4);
            rsum += __shfl_xor(rsum, 8);
            l_i[i] = l_i[i] * alpha + rsum;
            m_i[i] = mnew;
            #pragma unroll
            for (int j = 0; j < 4; ++j) o_acc[i][j] *= alpha;
        }

        // P -> LDS (transposed) for the PV matmul
        #pragma unroll
        for (int i = 0; i < 4; ++i)
            #pragma unroll
            for (int j = 0; j < 4; ++j)
                Ps[tx * 4 + j][ty * 4 + i] = s[i][j];
        __syncthreads();

        // O += P . V   (64x64x64)
        #pragma unroll 8
        for (int c = 0; c < 64; ++c) {
            const float4 pv = *(const float4*)&Ps[c][ty * 4];
            const float4 vv = *(const float4*)&Vs[c][tx * 4];
            const float pa[4] = {pv.x, pv.y, pv.z, pv.w};
            const float va[4] = {vv.x, vv.y, vv.z, vv.w};
            #pragma unroll
            for (int i = 0; i < 4; ++i)
                #pragma unroll
                for (int j = 0; j < 4; ++j)
                    o_acc[i][j] = fmaf(pa[i], va[j], o_acc[i][j]);
        }
    }

    #pragma unroll
    for (int i = 0; i < 4; ++i) {
        const float invl = 1.0f / l_i[i];
        const int m = q0 + ty * 4 + i;
        float4 v = make_float4(o_acc[i][0] * invl, o_acc[i][1] * invl,
                               o_acc[i][2] * invl, o_acc[i][3] * invl);
        *(float4*)&O[(size_t)m * DM + h * HD + tx * 4] = v;
    }
}

// ---------------------------------------------------------------------------
// Output projection: C = A(SEQ x DM) . wo(DM x DM)^T, row-major out.
// ---------------------------------------------------------------------------
__global__ __launch_bounds__(256)
void out_proj_kernel(const float* __restrict__ A,
                     const float* __restrict__ W,
                     float* __restrict__ C)
{
    __shared__ float As[64][65];
    __shared__ float Bs[64][65];
    const int tid = threadIdx.x;
    const int tx = tid & 15, ty = tid >> 4;
    const int mBase = blockIdx.x * 64;
    const int nBase = blockIdx.y * 64;

    float acc[4][4] = {};

    for (int k0 = 0; k0 < DM; k0 += 64) {
        #pragma unroll
        for (int l = 0; l < 16; ++l) {
            int idx = l * 256 + tid;
            int r = idx >> 6, c = idx & 63;
            As[c][r] = A[(size_t)(mBase + r) * DM + k0 + c];
            Bs[c][r] = W[(size_t)(nBase + r) * DM + k0 + c];
        }
        __syncthreads();
        #pragma unroll 16
        for (int kk = 0; kk < 64; ++kk) {
            const float4 av = *(const float4*)&As[kk][ty * 4];
            const float4 bv = *(const float4*)&Bs[kk][tx * 4];
            const float a[4] = {av.x, av.y, av.z, av.w};
            const float b[4] = {bv.x, bv.y, bv.z, bv.w};
            #pragma unroll
            for (int i = 0; i < 4; ++i)
                #pragma unroll
                for (int j = 0; j < 4; ++j)
                    acc[i][j] = fmaf(a[i], b[j], acc[i][j]);
        }
        __syncthreads();
    }

    #pragma unroll
    for (int i = 0; i < 4; ++i) {
        const int m = mBase + ty * 4 + i;
        float4 v = make_float4(acc[i][0], acc[i][1], acc[i][2], acc[i][3]);
        *(float4*)&C[(size_t)m * DM + nBase + tx * 4] = v;
    }
}

// ---------------------------------------------------------------------------
extern "C" void kernel_launch(void* const* d_in, const int* in_sizes, int n_in,
                              void* d_out, int out_size, void* d_ws, size_t ws_size,
                              hipStream_t stream) {
    (void)in_sizes; (void)n_in; (void)out_size; (void)ws_size;
    const float* x      = (const float*)d_in[0];
    const float* wq     = (const float*)d_in[1];
    const float* wk     = (const float*)d_in[2];
    const float* wv     = (const float*)d_in[3];
    const float* wo     = (const float*)d_in[4];
    const int*   tokpos = (const int*)d_in[5];
    float* out = (float*)d_out;

    const size_t plane = (size_t)SEQ * DM;   // 3,145,728 floats
    float* Qw = (float*)d_ws;                // [NH][SEQ][HD]
    float* Kw = Qw + plane;
    float* Vw = Kw + plane;
    float* Ow = Vw + plane;                  // [SEQ][DM]

    dim3 gQKV(SEQ / 64, NH, 3);
    qkv_rope_kernel<<<gQKV, 256, 0, stream>>>(x, wq, wk, wv, tokpos, Qw, Kw, Vw);

    dim3 gAttn(SEQ / 64, NH);
    attn_kernel<<<gAttn, 256, 0, stream>>>(Qw, Kw, Vw, Ow);

    dim3 gOut(SEQ / 64, DM / 64);
    out_proj_kernel<<<gOut, 256, 0, stream>>>(Ow, wo, out);
}

// Round 2
// 348.527 us; speedup vs baseline: 4.8480x; 4.8480x over previous
//
#include <hip/hip_runtime.h>
#include <math.h>

#define SEQ 4096
#define DM  768
#define NH  12
#define HD  64

using bf8 = __attribute__((ext_vector_type(8))) short;   // 8 bf16 = 4 VGPRs
using f4  = __attribute__((ext_vector_type(4))) float;   // 4 fp32 acc

__device__ __forceinline__ unsigned short f2bf(float f) {
    union { float f; unsigned int u; } v; v.f = f;
    unsigned int u = v.u + 0x7fffu + ((v.u >> 16) & 1u);   // RNE
    return (unsigned short)(u >> 16);
}

__device__ __forceinline__ f4 zero4() { f4 z = {0.f, 0.f, 0.f, 0.f}; return z; }

#define MFMA(a, b, c) __builtin_amdgcn_mfma_f32_16x16x32_bf16((a), (b), (c), 0, 0, 0)

// ---------------------------------------------------------------------------
// fp32 -> bf16 cast, 4 elems/thread
// ---------------------------------------------------------------------------
__global__ __launch_bounds__(256)
void cast_bf16_kernel(const float* __restrict__ in, unsigned short* __restrict__ out, int n4)
{
    int i = blockIdx.x * 256 + threadIdx.x;
    if (i < n4) {
        float4 v = ((const float4*)in)[i];
        ushort4 o;
        o.x = f2bf(v.x); o.y = f2bf(v.y); o.z = f2bf(v.z); o.w = f2bf(v.w);
        ((ushort4*)out)[i] = o;
    }
}

// ---------------------------------------------------------------------------
// QKV projection (MFMA) + fused RoPE.  C = x . W^T, 128x64 tile per block,
// N-tile == one head.  Output head-major bf16 [h][s][64].
// ---------------------------------------------------------------------------
#define LDA 72   // row stride (ushorts): 16B-aligned, breaks pow2 bank stride

__global__ __launch_bounds__(256)
void qkv_mfma_kernel(const unsigned short* __restrict__ xb,
                     const unsigned short* __restrict__ wqb,
                     const unsigned short* __restrict__ wkb,
                     const unsigned short* __restrict__ wvb,
                     const int*            __restrict__ tokpos,
                     unsigned short* __restrict__ Qo,
                     unsigned short* __restrict__ Ko,
                     unsigned short* __restrict__ Vo)
{
    __shared__ unsigned short As[128][LDA];
    __shared__ unsigned short Bs[64][LDA];
    const int tid  = threadIdx.x;
    const int wave = tid >> 6, lane = tid & 63;
    const int l15  = lane & 15, quad = lane >> 4;
    const int mBase = blockIdx.x * 128;
    const int h     = blockIdx.y;
    const int which = blockIdx.z;
    const unsigned short* __restrict__ W = (which == 0) ? wqb : (which == 1) ? wkb : wvb;
    unsigned short* __restrict__ C       = (which == 0) ? Qo  : (which == 1) ? Ko  : Vo;
    const int nBase = h * HD;

    f4 acc[2][4];
    #pragma unroll
    for (int mi = 0; mi < 2; ++mi)
        #pragma unroll
        for (int ni = 0; ni < 4; ++ni) acc[mi][ni] = zero4();

    for (int k0 = 0; k0 < DM; k0 += 64) {
        // stage A: 128x64 bf16, 16B chunks, coalesced
        #pragma unroll
        for (int t = 0; t < 4; ++t) {
            int idx = t * 256 + tid;                   // 0..1023
            int r = idx >> 3, cc = (idx & 7) * 8;
            *(uint4*)&As[r][cc] = *(const uint4*)&xb[(size_t)(mBase + r) * DM + k0 + cc];
        }
        // stage B: 64x64
        #pragma unroll
        for (int t = 0; t < 2; ++t) {
            int idx = t * 256 + tid;                   // 0..511
            int r = idx >> 3, cc = (idx & 7) * 8;
            *(uint4*)&Bs[r][cc] = *(const uint4*)&W[(size_t)(nBase + r) * DM + k0 + cc];
        }
        __syncthreads();
        #pragma unroll
        for (int ks = 0; ks < 2; ++ks) {
            bf8 a0 = *(const bf8*)&As[wave * 32 + l15][ks * 32 + quad * 8];
            bf8 a1 = *(const bf8*)&As[wave * 32 + 16 + l15][ks * 32 + quad * 8];
            #pragma unroll
            for (int ni = 0; ni < 4; ++ni) {
                bf8 b = *(const bf8*)&Bs[ni * 16 + l15][ks * 32 + quad * 8];
                acc[0][ni] = MFMA(a0, b, acc[0][ni]);
                acc[1][ni] = MFMA(a1, b, acc[1][ni]);
            }
        }
        __syncthreads();
    }

    // RoPE on q,k.  C layout: row=(quad*4+reg), col=ni*16+l15; pair partner is lane^1.
    if (which < 2) {
        #pragma unroll
        for (int mi = 0; mi < 2; ++mi) {
            #pragma unroll
            for (int reg = 0; reg < 4; ++reg) {
                const int rl = wave * 32 + mi * 16 + quad * 4 + reg;
                const float pos = (float)tokpos[mBase + rl];
                #pragma unroll
                for (int ni = 0; ni < 4; ++ni) {
                    float val = acc[mi][ni][reg];
                    float pv  = __shfl_xor(val, 1);
                    const int kf = (ni * 16 + l15) >> 1;       // pair index 0..31
                    const float invf = exp2f((float)kf * (-13.287712379549449f / 32.0f));
                    float sn, cs;
                    sincosf(pos * invf, &sn, &cs);
                    acc[mi][ni][reg] = (l15 & 1) ? fmaf(val, cs, pv * sn)
                                                 : fmaf(val, cs, -pv * sn);
                }
            }
        }
    }

    #pragma unroll
    for (int mi = 0; mi < 2; ++mi)
        #pragma unroll
        for (int ni = 0; ni < 4; ++ni)
            #pragma unroll
            for (int reg = 0; reg < 4; ++reg) {
                const int rl = wave * 32 + mi * 16 + quad * 4 + reg;
                C[((size_t)h * SEQ + mBase + rl) * HD + ni * 16 + l15] = f2bf(acc[mi][ni][reg]);
            }
}

// ---------------------------------------------------------------------------
// Flash attention, bf16 MFMA.  Block = (head, 64-query tile), 4 waves;
// wave w owns query rows w*16..w*16+15.  Q frags live in registers.
// ---------------------------------------------------------------------------
#define VT_OFF(d) ((d) * LDA + ((d) >> 3) * 8)   // skew: breaks 8-way scatter conflict

__global__ __launch_bounds__(256)
void attn_mfma_kernel(const unsigned short* __restrict__ Q,
                      const unsigned short* __restrict__ K,
                      const unsigned short* __restrict__ V,
                      unsigned short* __restrict__ O)    // [SEQ][DM] bf16
{
    __shared__ unsigned short Ks[64][LDA];               // [key][dim]
    __shared__ unsigned short Vt[64 * LDA + 64];         // [dim][key], skewed
    __shared__ unsigned short Ps[4][16][LDA];            // per-wave P, [row][key]
    const int tid  = threadIdx.x;
    const int wave = tid >> 6, lane = tid & 63;
    const int l15  = lane & 15, quad = lane >> 4;
    const int h  = blockIdx.y;
    const int qb = (int)gridDim.x - 1 - (int)blockIdx.x; // heavy blocks first
    const int q0 = qb * 64;
    const unsigned short* __restrict__ Qh = Q + (size_t)h * SEQ * HD;
    const unsigned short* __restrict__ Kh = K + (size_t)h * SEQ * HD;
    const unsigned short* __restrict__ Vh = V + (size_t)h * SEQ * HD;

    // Q fragments: A[m=l15][k=quad*8+j], 2 k-substeps — register-resident
    bf8 qf[2];
    #pragma unroll
    for (int ks = 0; ks < 2; ++ks)
        qf[ks] = *(const bf8*)&Qh[(size_t)(q0 + wave * 16 + l15) * HD + ks * 32 + quad * 8];

    f4 o_acc[4];
    #pragma unroll
    for (int ni = 0; ni < 4; ++ni) o_acc[ni] = zero4();
    float m_i[4], l_i[4];
    #pragma unroll
    for (int r = 0; r < 4; ++r) { m_i[r] = -1e30f; l_i[r] = 0.0f; }

    #pragma unroll 1
    for (int kb = 0; kb <= qb; ++kb) {
        __syncthreads();   // prior-iter PV reads of Vt/Ps done before restage
        #pragma unroll
        for (int t = 0; t < 2; ++t) {
            int idx = t * 256 + tid;                     // 0..511
            int r = idx >> 3, cc = (idx & 7) * 8;
            *(uint4*)&Ks[r][cc] = *(const uint4*)&Kh[(size_t)(kb * 64 + r) * HD + cc];
            uint4 raw = *(const uint4*)&Vh[(size_t)(kb * 64 + r) * HD + cc];
            const unsigned short* p = (const unsigned short*)&raw;
            #pragma unroll
            for (int j = 0; j < 8; ++j) Vt[VT_OFF(cc + j) + r] = p[j];
        }
        __syncthreads();

        // S = Q.K^T : B[k][n]=K[n][k] -> contiguous read from Ks[n][k]
        f4 s[4];
        #pragma unroll
        for (int ni = 0; ni < 4; ++ni) s[ni] = zero4();
        #pragma unroll
        for (int ks = 0; ks < 2; ++ks) {
            #pragma unroll
            for (int ni = 0; ni < 4; ++ni) {
                bf8 b = *(const bf8*)&Ks[ni * 16 + l15][ks * 32 + quad * 8];
                s[ni] = MFMA(qf[ks], b, s[ni]);
            }
        }

        // scale + causal mask (diagonal block only)
        const bool diag = (kb == qb);
        #pragma unroll
        for (int ni = 0; ni < 4; ++ni)
            #pragma unroll
            for (int reg = 0; reg < 4; ++reg) {
                float val = s[ni][reg] * 0.125f;
                if (diag && (ni * 16 + l15) > (wave * 16 + quad * 4 + reg)) val = -1e30f;
                s[ni][reg] = val;
            }

        // online softmax; row's 64 cols live in the 16-lane l15 group
        #pragma unroll
        for (int reg = 0; reg < 4; ++reg) {
            float rmax = fmaxf(fmaxf(s[0][reg], s[1][reg]), fmaxf(s[2][reg], s[3][reg]));
            rmax = fmaxf(rmax, __shfl_xor(rmax, 1));
            rmax = fmaxf(rmax, __shfl_xor(rmax, 2));
            rmax = fmaxf(rmax, __shfl_xor(rmax, 4));
            rmax = fmaxf(rmax, __shfl_xor(rmax, 8));
            const float mnew  = fmaxf(m_i[reg], rmax);
            const float alpha = __expf(m_i[reg] - mnew);
            float rsum = 0.f;
            #pragma unroll
            for (int ni = 0; ni < 4; ++ni) {
                float e = __expf(s[ni][reg] - mnew);
                s[ni][reg] = e;
                rsum += e;
            }
            rsum += __shfl_xor(rsum, 1);
            rsum += __shfl_xor(rsum, 2);
            rsum += __shfl_xor(rsum, 4);
            rsum += __shfl_xor(rsum, 8);
            l_i[reg] = l_i[reg] * alpha + rsum;
            m_i[reg] = mnew;
            #pragma unroll
            for (int ni = 0; ni < 4; ++ni) o_acc[ni][reg] *= alpha;
        }

        // P -> LDS bf16 (C layout -> A layout via round-trip)
        #pragma unroll
        for (int ni = 0; ni < 4; ++ni)
            #pragma unroll
            for (int reg = 0; reg < 4; ++reg)
                Ps[wave][quad * 4 + reg][ni * 16 + l15] = f2bf(s[ni][reg]);
        __syncthreads();

        // O += P.V : A from Ps, B[k][n]=V[k][n] -> contiguous read from Vt[n][k]
        #pragma unroll
        for (int ks = 0; ks < 2; ++ks) {
            bf8 pa = *(const bf8*)&Ps[wave][l15][ks * 32 + quad * 8];
            #pragma unroll
            for (int ni = 0; ni < 4; ++ni) {
                bf8 vb = *(const bf8*)&Vt[VT_OFF(ni * 16 + l15) + ks * 32 + quad * 8];
                o_acc[ni] = MFMA(pa, vb, o_acc[ni]);
            }
        }
    }

    #pragma unroll
    for (int reg = 0; reg < 4; ++reg) {
        const float invl = 1.0f / l_i[reg];
        const int row = q0 + wave * 16 + quad * 4 + reg;
        #pragma unroll
        for (int ni = 0; ni < 4; ++ni)
            O[(size_t)row * DM + h * HD + ni * 16 + l15] = f2bf(o_acc[ni][reg] * invl);
    }
}

// ---------------------------------------------------------------------------
// Output projection (MFMA): C = O . wo^T, fp32 out.  128x64 tile per block.
// ---------------------------------------------------------------------------
__global__ __launch_bounds__(256)
void proj_mfma_kernel(const unsigned short* __restrict__ Ab,
                      const unsigned short* __restrict__ Wb,
                      float* __restrict__ C)
{
    __shared__ unsigned short As[128][LDA];
    __shared__ unsigned short Bs[64][LDA];
    const int tid  = threadIdx.x;
    const int wave = tid >> 6, lane = tid & 63;
    const int l15  = lane & 15, quad = lane >> 4;
    const int mBase = blockIdx.x * 128;
    const int nBase = blockIdx.y * 64;

    f4 acc[2][4];
    #pragma unroll
    for (int mi = 0; mi < 2; ++mi)
        #pragma unroll
        for (int ni = 0; ni < 4; ++ni) acc[mi][ni] = zero4();

    for (int k0 = 0; k0 < DM; k0 += 64) {
        #pragma unroll
        for (int t = 0; t < 4; ++t) {
            int idx = t * 256 + tid;
            int r = idx >> 3, cc = (idx & 7) * 8;
            *(uint4*)&As[r][cc] = *(const uint4*)&Ab[(size_t)(mBase + r) * DM + k0 + cc];
        }
        #pragma unroll
        for (int t = 0; t < 2; ++t) {
            int idx = t * 256 + tid;
            int r = idx >> 3, cc = (idx & 7) * 8;
            *(uint4*)&Bs[r][cc] = *(const uint4*)&Wb[(size_t)(nBase + r) * DM + k0 + cc];
        }
        __syncthreads();
        #pragma unroll
        for (int ks = 0; ks < 2; ++ks) {
            bf8 a0 = *(const bf8*)&As[wave * 32 + l15][ks * 32 + quad * 8];
            bf8 a1 = *(const bf8*)&As[wave * 32 + 16 + l15][ks * 32 + quad * 8];
            #pragma unroll
            for (int ni = 0; ni < 4; ++ni) {
                bf8 b = *(const bf8*)&Bs[ni * 16 + l15][ks * 32 + quad * 8];
                acc[0][ni] = MFMA(a0, b, acc[0][ni]);
                acc[1][ni] = MFMA(a1, b, acc[1][ni]);
            }
        }
        __syncthreads();
    }

    #pragma unroll
    for (int mi = 0; mi < 2; ++mi)
        #pragma unroll
        for (int ni = 0; ni < 4; ++ni)
            #pragma unroll
            for (int reg = 0; reg < 4; ++reg) {
                const int m = mBase + wave * 32 + mi * 16 + quad * 4 + reg;
                C[(size_t)m * DM + nBase + ni * 16 + l15] = acc[mi][ni][reg];
            }
}

// ---------------------------------------------------------------------------
extern "C" void kernel_launch(void* const* d_in, const int* in_sizes, int n_in,
                              void* d_out, int out_size, void* d_ws, size_t ws_size,
                              hipStream_t stream) {
    (void)in_sizes; (void)n_in; (void)out_size; (void)ws_size;
    const float* x      = (const float*)d_in[0];
    const float* wq     = (const float*)d_in[1];
    const float* wk     = (const float*)d_in[2];
    const float* wv     = (const float*)d_in[3];
    const float* wo     = (const float*)d_in[4];
    const int*   tokpos = (const int*)d_in[5];
    float* out = (float*)d_out;

    unsigned short* p = (unsigned short*)d_ws;
    const size_t xN = (size_t)SEQ * DM;       // 3,145,728
    const size_t wN = (size_t)DM * DM;        //   589,824
    unsigned short* xb  = p;            p += xN;
    unsigned short* wqb = p;            p += wN;
    unsigned short* wkb = p;            p += wN;
    unsigned short* wvb = p;            p += wN;
    unsigned short* wob = p;            p += wN;
    unsigned short* Qb  = p;            p += xN;   // [h][s][64]
    unsigned short* Kb  = p;            p += xN;
    unsigned short* Vb  = p;            p += xN;
    unsigned short* Ob  = p;            p += xN;   // [s][768]

    cast_bf16_kernel<<<(xN / 4 + 255) / 256, 256, 0, stream>>>(x,  xb,  (int)(xN / 4));
    cast_bf16_kernel<<<(wN / 4 + 255) / 256, 256, 0, stream>>>(wq, wqb, (int)(wN / 4));
    cast_bf16_kernel<<<(wN / 4 + 255) / 256, 256, 0, stream>>>(wk, wkb, (int)(wN / 4));
    cast_bf16_kernel<<<(wN / 4 + 255) / 256, 256, 0, stream>>>(wv, wvb, (int)(wN / 4));
    cast_bf16_kernel<<<(wN / 4 + 255) / 256, 256, 0, stream>>>(wo, wob, (int)(wN / 4));

    dim3 gQKV(SEQ / 128, NH, 3);
    qkv_mfma_kernel<<<gQKV, 256, 0, stream>>>(xb, wqb, wkb, wvb, tokpos, Qb, Kb, Vb);

    dim3 gAttn(SEQ / 64, NH);
    attn_mfma_kernel<<<gAttn, 256, 0, stream>>>(Qb, Kb, Vb, Ob);

    dim3 gProj(SEQ / 128, DM / 64);
    proj_mfma_kernel<<<gProj, 256, 0, stream>>>(Ob, wob, out);
}

// Round 3
// 251.335 us; speedup vs baseline: 6.7227x; 1.3867x over previous
//
#include <hip/hip_runtime.h>
#include <math.h>

#define SEQ 4096
#define DM  768
#define NH  12
#define HD  64

using bf8 = __attribute__((ext_vector_type(8))) short;   // 8 bf16 = 4 VGPRs
using f4  = __attribute__((ext_vector_type(4))) float;   // 4 fp32 acc

__device__ __forceinline__ unsigned short f2bf(float f) {
    union { float f; unsigned int u; } v; v.f = f;
    unsigned int u = v.u + 0x7fffu + ((v.u >> 16) & 1u);   // RNE
    return (unsigned short)(u >> 16);
}

__device__ __forceinline__ f4 zero4() { f4 z = {0.f, 0.f, 0.f, 0.f}; return z; }

#define MFMA(a, b, c) __builtin_amdgcn_mfma_f32_16x16x32_bf16((a), (b), (c), 0, 0, 0)

#define QSCALE 0.18033688011112042f     // 0.125 * log2(e)
#define SHIFT  23.083120654223414f      // 16 * log2(e)
#define LDA 72                          // LDS row stride (shorts)

// ---------------------------------------------------------------------------
// RoPE cos/sin tables: [4096][32] fp32 each.
// ---------------------------------------------------------------------------
__global__ __launch_bounds__(256)
void rope_table_kernel(float* __restrict__ CS, float* __restrict__ SN)
{
    int idx = blockIdx.x * 256 + threadIdx.x;      // 0 .. 131071
    int pos = idx >> 5, kf = idx & 31;
    float inv = exp2f((float)kf * (-13.287712379549449f / 32.0f));
    float sn, cs;
    sincosf((float)pos * inv, &sn, &cs);
    CS[idx] = cs; SN[idx] = sn;
}

// ---------------------------------------------------------------------------
// Fused fp32 -> bf16 cast of x + 4 weight matrices (one launch).
// ---------------------------------------------------------------------------
#define NX4 (SEQ * DM / 4)      // 786432
#define NW4 (DM * DM / 4)       // 147456

__global__ __launch_bounds__(256)
void cast_all_kernel(const float* __restrict__ x,  const float* __restrict__ wq,
                     const float* __restrict__ wk, const float* __restrict__ wv,
                     const float* __restrict__ wo,
                     unsigned short* __restrict__ xb,  unsigned short* __restrict__ wqb,
                     unsigned short* __restrict__ wkb, unsigned short* __restrict__ wvb,
                     unsigned short* __restrict__ wob)
{
    int i = blockIdx.x * 256 + threadIdx.x;
    const float* src; unsigned short* dst; int j = i;
    if (j < NX4)            { src = x;  dst = xb;  }
    else { j -= NX4;
    if (j < NW4)            { src = wq; dst = wqb; }
    else { j -= NW4;
    if (j < NW4)            { src = wk; dst = wkb; }
    else { j -= NW4;
    if (j < NW4)            { src = wv; dst = wvb; }
    else { j -= NW4;          src = wo; dst = wob; } } } }
    float4 v = ((const float4*)src)[j];
    ushort4 o;
    o.x = f2bf(v.x); o.y = f2bf(v.y); o.z = f2bf(v.z); o.w = f2bf(v.w);
    ((ushort4*)dst)[j] = o;
}

// ---------------------------------------------------------------------------
// QKV projection (MFMA) + fused RoPE (table) + Q pre-scale + V transpose.
// Q,K out: [h][s][64] bf16.  V out: [h][64][4096] bf16 (dim-major).
// ---------------------------------------------------------------------------
__global__ __launch_bounds__(256)
void qkv_mfma_kernel(const unsigned short* __restrict__ xb,
                     const unsigned short* __restrict__ wqb,
                     const unsigned short* __restrict__ wkb,
                     const unsigned short* __restrict__ wvb,
                     const int*            __restrict__ tokpos,
                     const float*          __restrict__ CS,
                     const float*          __restrict__ SN,
                     unsigned short* __restrict__ Qo,
                     unsigned short* __restrict__ Ko,
                     unsigned short* __restrict__ VoT)
{
    __shared__ unsigned short As[128][LDA];
    __shared__ unsigned short Bs[64][LDA];
    const int tid  = threadIdx.x;
    const int wave = tid >> 6, lane = tid & 63;
    const int l15  = lane & 15, quad = lane >> 4;
    const int mBase = blockIdx.x * 128;
    const int h     = blockIdx.y;
    const int which = blockIdx.z;
    const unsigned short* __restrict__ W = (which == 0) ? wqb : (which == 1) ? wkb : wvb;
    const int nBase = h * HD;

    f4 acc[2][4];
    #pragma unroll
    for (int mi = 0; mi < 2; ++mi)
        #pragma unroll
        for (int ni = 0; ni < 4; ++ni) acc[mi][ni] = zero4();

    for (int k0 = 0; k0 < DM; k0 += 64) {
        #pragma unroll
        for (int t = 0; t < 4; ++t) {
            int idx = t * 256 + tid;
            int r = idx >> 3, cc = (idx & 7) * 8;
            *(uint4*)&As[r][cc] = *(const uint4*)&xb[(size_t)(mBase + r) * DM + k0 + cc];
        }
        #pragma unroll
        for (int t = 0; t < 2; ++t) {
            int idx = t * 256 + tid;
            int r = idx >> 3, cc = (idx & 7) * 8;
            *(uint4*)&Bs[r][cc] = *(const uint4*)&W[(size_t)(nBase + r) * DM + k0 + cc];
        }
        __syncthreads();
        #pragma unroll
        for (int ks = 0; ks < 2; ++ks) {
            bf8 a0 = *(const bf8*)&As[wave * 32 + l15][ks * 32 + quad * 8];
            bf8 a1 = *(const bf8*)&As[wave * 32 + 16 + l15][ks * 32 + quad * 8];
            #pragma unroll
            for (int ni = 0; ni < 4; ++ni) {
                bf8 b = *(const bf8*)&Bs[ni * 16 + l15][ks * 32 + quad * 8];
                acc[0][ni] = MFMA(a0, b, acc[0][ni]);
                acc[1][ni] = MFMA(a1, b, acc[1][ni]);
            }
        }
        __syncthreads();
    }

    if (which < 2) {
        // RoPE via table; pair partner is lane^1.  Scale Q by QSCALE.
        unsigned short* __restrict__ C = (which == 0) ? Qo : Ko;
        const float sc = (which == 0) ? QSCALE : 1.0f;
        #pragma unroll
        for (int mi = 0; mi < 2; ++mi) {
            #pragma unroll
            for (int reg = 0; reg < 4; ++reg) {
                const int rl = wave * 32 + mi * 16 + quad * 4 + reg;
                const int tb = tokpos[mBase + rl] * 32;
                #pragma unroll
                for (int ni = 0; ni < 4; ++ni) {
                    const int col = ni * 16 + l15;
                    const float cs = CS[tb + (col >> 1)];
                    const float sn = SN[tb + (col >> 1)];
                    float val = acc[mi][ni][reg];
                    float pv  = __shfl_xor(val, 1);
                    float res = (l15 & 1) ? fmaf(val, cs, pv * sn)
                                          : fmaf(val, cs, -pv * sn);
                    C[((size_t)h * SEQ + mBase + rl) * HD + col] = f2bf(res * sc);
                }
            }
        }
    } else {
        // V: transpose 128x64 tile through LDS, store [h][64][4096] coalesced.
        unsigned short* Tt = (unsigned short*)As;       // 64 x 128, stride 136
        #pragma unroll
        for (int mi = 0; mi < 2; ++mi)
            #pragma unroll
            for (int ni = 0; ni < 4; ++ni)
                #pragma unroll
                for (int reg = 0; reg < 4; ++reg) {
                    const int m = wave * 32 + mi * 16 + quad * 4 + reg;
                    Tt[(ni * 16 + l15) * 136 + m] = f2bf(acc[mi][ni][reg]);
                }
        __syncthreads();
        #pragma unroll
        for (int t = 0; t < 4; ++t) {
            int idx = t * 256 + tid;                    // 0..1023
            int r = idx >> 4, c = (idx & 15) * 8;
            uint4 v = *(const uint4*)&Tt[r * 136 + c];
            *(uint4*)&VoT[((size_t)h * HD + r) * SEQ + mBase + c] = v;
        }
    }
}

// ---------------------------------------------------------------------------
// Flash attention, bf16 MFMA, fixed-shift softmax (no in-loop reductions).
// Block = (head, 64-query tile), 4 waves; wave w owns query rows w*16..+15.
// K/V staged with register double-buffer; V comes pre-transposed.
// ---------------------------------------------------------------------------
__global__ __launch_bounds__(256)
void attn_mfma_kernel(const unsigned short* __restrict__ Q,
                      const unsigned short* __restrict__ K,
                      const unsigned short* __restrict__ VT,  // [h][64][4096]
                      unsigned short* __restrict__ O)          // [SEQ][DM]
{
    __shared__ unsigned short Ks[64][LDA];               // [key][dim]
    __shared__ unsigned short Vt[64][LDA];               // [dim][key]
    __shared__ unsigned short Ps[4][16][LDA];            // per-wave P [row][key]
    const int tid  = threadIdx.x;
    const int wave = tid >> 6, lane = tid & 63;
    const int l15  = lane & 15, quad = lane >> 4;
    const int h  = blockIdx.y;
    const int qb = (int)gridDim.x - 1 - (int)blockIdx.x; // heavy blocks first
    const int q0 = qb * 64;
    const unsigned short* __restrict__ Qh = Q  + (size_t)h * SEQ * HD;
    const unsigned short* __restrict__ Kh = K  + (size_t)h * SEQ * HD;
    const unsigned short* __restrict__ Vh = VT + (size_t)h * HD * SEQ;

    // Q fragments (A layout), register-resident; Q already scaled by QSCALE.
    bf8 qf[2];
    #pragma unroll
    for (int ks = 0; ks < 2; ++ks)
        qf[ks] = *(const bf8*)&Qh[(size_t)(q0 + wave * 16 + l15) * HD + ks * 32 + quad * 8];

    // staging assignment: 2 x 16B chunks each for K and V^T
    const int r0 = tid >> 3, c0 = (tid & 7) * 8;         // rows 0..31
    const int r1 = r0 + 32;                              // rows 32..63
    uint4 kr0 = *(const uint4*)&Kh[(size_t)r0 * HD + c0];
    uint4 kr1 = *(const uint4*)&Kh[(size_t)r1 * HD + c0];
    uint4 vr0 = *(const uint4*)&Vh[(size_t)r0 * SEQ + c0];
    uint4 vr1 = *(const uint4*)&Vh[(size_t)r1 * SEQ + c0];

    f4 o_acc[4];
    #pragma unroll
    for (int ni = 0; ni < 4; ++ni) o_acc[ni] = zero4();
    float l_lane[4] = {0.f, 0.f, 0.f, 0.f};

    #pragma unroll 1
    for (int kb = 0; kb <= qb; ++kb) {
        __syncthreads();   // prior-iter reads of Ks/Vt done
        *(uint4*)&Ks[r0][c0] = kr0;
        *(uint4*)&Ks[r1][c0] = kr1;
        *(uint4*)&Vt[r0][c0] = vr0;
        *(uint4*)&Vt[r1][c0] = vr1;
        __syncthreads();

        if (kb < qb) {                                   // prefetch next tile
            const int nk = (kb + 1) * 64;
            kr0 = *(const uint4*)&Kh[(size_t)(nk + r0) * HD + c0];
            kr1 = *(const uint4*)&Kh[(size_t)(nk + r1) * HD + c0];
            vr0 = *(const uint4*)&Vh[(size_t)r0 * SEQ + nk + c0];
            vr1 = *(const uint4*)&Vh[(size_t)r1 * SEQ + nk + c0];
        }

        // S' = (Q*QSCALE) . K^T   (= score * 0.125 * log2e)
        f4 s[4];
        #pragma unroll
        for (int ni = 0; ni < 4; ++ni) s[ni] = zero4();
        #pragma unroll
        for (int ks = 0; ks < 2; ++ks) {
            #pragma unroll
            for (int ni = 0; ni < 4; ++ni) {
                bf8 b = *(const bf8*)&Ks[ni * 16 + l15][ks * 32 + quad * 8];
                s[ni] = MFMA(qf[ks], b, s[ni]);
            }
        }

        // fixed-shift softmax: p = 2^(s' - 16*log2e); no reductions in loop
        #pragma unroll
        for (int ni = 0; ni < 4; ++ni)
            #pragma unroll
            for (int reg = 0; reg < 4; ++reg)
                s[ni][reg] = exp2f(s[ni][reg] - SHIFT);
        if (kb == qb) {                                  // causal mask, diag only
            #pragma unroll
            for (int ni = 0; ni < 4; ++ni)
                #pragma unroll
                for (int reg = 0; reg < 4; ++reg)
                    if ((ni * 16 + l15) > (wave * 16 + quad * 4 + reg))
                        s[ni][reg] = 0.f;
        }
        #pragma unroll
        for (int ni = 0; ni < 4; ++ni)
            #pragma unroll
            for (int reg = 0; reg < 4; ++reg) {
                l_lane[reg] += s[ni][reg];
                Ps[wave][quad * 4 + reg][ni * 16 + l15] = f2bf(s[ni][reg]);
            }
        // Ps is wave-private: LDS in-wave write->read needs only lgkmcnt(0)
        asm volatile("s_waitcnt lgkmcnt(0)" ::: "memory");

        // O += P.V  (B read from pre-transposed Vt)
        #pragma unroll
        for (int ks = 0; ks < 2; ++ks) {
            bf8 pa = *(const bf8*)&Ps[wave][l15][ks * 32 + quad * 8];
            #pragma unroll
            for (int ni = 0; ni < 4; ++ni) {
                bf8 vb = *(const bf8*)&Vt[ni * 16 + l15][ks * 32 + quad * 8];
                o_acc[ni] = MFMA(pa, vb, o_acc[ni]);
            }
        }
    }

    // single post-loop row-sum reduction over the 16-lane l15 group
    #pragma unroll
    for (int reg = 0; reg < 4; ++reg) {
        float l = l_lane[reg];
        l += __shfl_xor(l, 1);
        l += __shfl_xor(l, 2);
        l += __shfl_xor(l, 4);
        l += __shfl_xor(l, 8);
        const float invl = 1.0f / l;
        const int row = q0 + wave * 16 + quad * 4 + reg;
        #pragma unroll
        for (int ni = 0; ni < 4; ++ni)
            O[(size_t)row * DM + h * HD + ni * 16 + l15] = f2bf(o_acc[ni][reg] * invl);
    }
}

// ---------------------------------------------------------------------------
// Output projection (MFMA): C = O . wo^T, fp32 out.  128x64 tile per block.
// ---------------------------------------------------------------------------
__global__ __launch_bounds__(256)
void proj_mfma_kernel(const unsigned short* __restrict__ Ab,
                      const unsigned short* __restrict__ Wb,
                      float* __restrict__ C)
{
    __shared__ unsigned short As[128][LDA];
    __shared__ unsigned short Bs[64][LDA];
    const int tid  = threadIdx.x;
    const int wave = tid >> 6, lane = tid & 63;
    const int l15  = lane & 15, quad = lane >> 4;
    const int mBase = blockIdx.x * 128;
    const int nBase = blockIdx.y * 64;

    f4 acc[2][4];
    #pragma unroll
    for (int mi = 0; mi < 2; ++mi)
        #pragma unroll
        for (int ni = 0; ni < 4; ++ni) acc[mi][ni] = zero4();

    for (int k0 = 0; k0 < DM; k0 += 64) {
        #pragma unroll
        for (int t = 0; t < 4; ++t) {
            int idx = t * 256 + tid;
            int r = idx >> 3, cc = (idx & 7) * 8;
            *(uint4*)&As[r][cc] = *(const uint4*)&Ab[(size_t)(mBase + r) * DM + k0 + cc];
        }
        #pragma unroll
        for (int t = 0; t < 2; ++t) {
            int idx = t * 256 + tid;
            int r = idx >> 3, cc = (idx & 7) * 8;
            *(uint4*)&Bs[r][cc] = *(const uint4*)&Wb[(size_t)(nBase + r) * DM + k0 + cc];
        }
        __syncthreads();
        #pragma unroll
        for (int ks = 0; ks < 2; ++ks) {
            bf8 a0 = *(const bf8*)&As[wave * 32 + l15][ks * 32 + quad * 8];
            bf8 a1 = *(const bf8*)&As[wave * 32 + 16 + l15][ks * 32 + quad * 8];
            #pragma unroll
            for (int ni = 0; ni < 4; ++ni) {
                bf8 b = *(const bf8*)&Bs[ni * 16 + l15][ks * 32 + quad * 8];
                acc[0][ni] = MFMA(a0, b, acc[0][ni]);
                acc[1][ni] = MFMA(a1, b, acc[1][ni]);
            }
        }
        __syncthreads();
    }

    #pragma unroll
    for (int mi = 0; mi < 2; ++mi)
        #pragma unroll
        for (int ni = 0; ni < 4; ++ni)
            #pragma unroll
            for (int reg = 0; reg < 4; ++reg) {
                const int m = mBase + wave * 32 + mi * 16 + quad * 4 + reg;
                C[(size_t)m * DM + nBase + ni * 16 + l15] = acc[mi][ni][reg];
            }
}

// ---------------------------------------------------------------------------
extern "C" void kernel_launch(void* const* d_in, const int* in_sizes, int n_in,
                              void* d_out, int out_size, void* d_ws, size_t ws_size,
                              hipStream_t stream) {
    (void)in_sizes; (void)n_in; (void)out_size; (void)ws_size;
    const float* x      = (const float*)d_in[0];
    const float* wq     = (const float*)d_in[1];
    const float* wk     = (const float*)d_in[2];
    const float* wv     = (const float*)d_in[3];
    const float* wo     = (const float*)d_in[4];
    const int*   tokpos = (const int*)d_in[5];
    float* out = (float*)d_out;

    float* CS = (float*)d_ws;                       // [4096][32]
    float* SN = CS + 4096 * 32;
    unsigned short* p = (unsigned short*)(SN + 4096 * 32);
    const size_t xN = (size_t)SEQ * DM;             // 3,145,728
    const size_t wN = (size_t)DM * DM;              //   589,824
    unsigned short* xb  = p;            p += xN;
    unsigned short* wqb = p;            p += wN;
    unsigned short* wkb = p;            p += wN;
    unsigned short* wvb = p;            p += wN;
    unsigned short* wob = p;            p += wN;
    unsigned short* Qb  = p;            p += xN;    // [h][s][64]
    unsigned short* Kb  = p;            p += xN;    // [h][s][64]
    unsigned short* VbT = p;            p += xN;    // [h][64][4096]
    unsigned short* Ob  = p;            p += xN;    // [s][768]

    rope_table_kernel<<<512, 256, 0, stream>>>(CS, SN);
    cast_all_kernel<<<(NX4 + 4 * NW4) / 256, 256, 0, stream>>>(
        x, wq, wk, wv, wo, xb, wqb, wkb, wvb, wob);

    dim3 gQKV(SEQ / 128, NH, 3);
    qkv_mfma_kernel<<<gQKV, 256, 0, stream>>>(xb, wqb, wkb, wvb, tokpos, CS, SN,
                                              Qb, Kb, VbT);

    dim3 gAttn(SEQ / 64, NH);
    attn_mfma_kernel<<<gAttn, 256, 0, stream>>>(Qb, Kb, VbT, Ob);

    dim3 gProj(SEQ / 128, DM / 64);
    proj_mfma_kernel<<<gProj, 256, 0, stream>>>(Ob, wob, out);
}